// Round 12
// baseline (647.653 us; speedup 1.0000x reference)
//
#include <hip/hip_runtime.h>
#include <math.h>

#define DIM 1024
#define NQ 8192
#define NK 8192

typedef unsigned short u16;
typedef __attribute__((ext_vector_type(8))) short short8;
typedef __attribute__((ext_vector_type(8))) u16 u16x8;
typedef __attribute__((ext_vector_type(4))) u16 u16x4;
typedef __attribute__((ext_vector_type(4))) float f32x4;
typedef __attribute__((address_space(1))) const unsigned int gu32;
typedef __attribute__((address_space(3))) unsigned int lu32;

__device__ inline u16 f2bf(float f) {
  unsigned u = __builtin_bit_cast(unsigned, f);
  u += 0x7fff + ((u >> 16) & 1);
  return (u16)(u >> 16);
}
__device__ inline float bf2f(u16 h) {
  unsigned u = ((unsigned)h) << 16;
  return __builtin_bit_cast(float, u);
}

// ---------------- small kernels: var -> MLP -> bias_weight ----------------

// fallback-only separate var pass
__global__ void var_partial_kernel(const float* __restrict__ k,
                                   float* __restrict__ ps, float* __restrict__ pq) {
  int col = blockIdx.x * 256 + threadIdx.x;
  int r0  = blockIdx.y * 256;
  float s = 0.f, q = 0.f;
  for (int r = 0; r < 256; ++r) {
    float x = k[(size_t)(r0 + r) * DIM + col];
    s += x; q += x * x;
  }
  ps[blockIdx.y * DIM + col] = s;
  pq[blockIdx.y * DIM + col] = q;
}

__global__ void gfv_kernel(const float* __restrict__ ps, const float* __restrict__ pq,
                           float* __restrict__ gfv, int np) {
  int col = blockIdx.x * 256 + threadIdx.x;
  float s = 0.f, q = 0.f;
  for (int c = 0; c < np; ++c) { s += ps[(size_t)c * DIM + col]; q += pq[(size_t)c * DIM + col]; }
  const float n = 8192.f;
  gfv[col] = (q - s * s / n) / (n - 1.f);  // unbiased var (ddof=1)
}

__global__ void h1_partial_kernel(const float* __restrict__ gfv, const float* __restrict__ W1,
                                  float* __restrict__ h1p) {
  int j  = blockIdx.x * 256 + threadIdx.x;
  int d0 = blockIdx.y * 128;
  float acc = 0.f;
  for (int d = 0; d < 128; ++d)
    acc += gfv[d0 + d] * W1[(size_t)(d0 + d) * 2048 + j];
  h1p[blockIdx.y * 2048 + j] = acc;
}

__global__ void bw_kernel(const float* __restrict__ h1p, const float* __restrict__ b1,
                          const float* __restrict__ W2, const float* __restrict__ b2,
                          float* __restrict__ bw) {
  __shared__ float red[256];
  int t = threadIdx.x;
  float acc = 0.f;
  for (int i = 0; i < 8; ++i) {
    int j = i * 256 + t;
    float h = b1[j];
    for (int c = 0; c < 8; ++c) h += h1p[c * 2048 + j];
    h = fmaxf(h, 0.f);
    acc += h * W2[j];
  }
  red[t] = acc; __syncthreads();
  for (int s = 128; s > 0; s >>= 1) { if (t < s) red[t] += red[t + s]; __syncthreads(); }
  if (t == 0) bw[0] = 1.f / (1.f + __expf(-(red[0] + b2[0])));
}

// centers: unscaled (cq,cr for fallback) + scaled by bw*log2e (cqs,crs for fused path)
__global__ void centers_kernel(const float4* __restrict__ qb, const float4* __restrict__ rb,
                               const float* __restrict__ bwp,
                               float2* __restrict__ cq, float2* __restrict__ cr,
                               float2* __restrict__ cqs, float2* __restrict__ crs) {
  int i = blockIdx.x * 256 + threadIdx.x;
  const float sc = bwp[0] * 1.44269504f;
  float4 a = qb[i];
  float2 c1 = make_float2(0.5f * (a.x + a.z), 0.5f * (a.y + a.w));
  cq[i] = c1;
  cqs[i] = make_float2(c1.x * sc, c1.y * sc);
  float4 b = rb[i];
  float2 c2 = make_float2(0.5f * (b.x + b.z), 0.5f * (b.y + b.w));
  cr[i] = c2;
  crs[i] = make_float2(c2.x * sc, c2.y * sc);
}

// ---------------- conversion kernels (fused launches) ----------------
// y==1 (k) branch optionally fuses var partial sums: thread (b,t) covers
// rows {b, b+1024, ..., b+7168} x cols {4t..4t+3} -> psB[b][4t..4t+3].

__global__ void f2bf3_kernel(const float4* __restrict__ a, const float4* __restrict__ b,
                             const float4* __restrict__ c, u16x4* __restrict__ oa,
                             u16x4* __restrict__ ob, u16x4* __restrict__ oc, int n4,
                             float* __restrict__ psB, float* __restrict__ pqB) {
  const float4* in = (blockIdx.y == 0) ? a : (blockIdx.y == 1) ? b : c;
  u16x4* out = (blockIdx.y == 0) ? oa : (blockIdx.y == 1) ? ob : oc;
  if (blockIdx.y == 1 && psB) {
    const int t = threadIdx.x, blk = blockIdx.x;
    float4 s = make_float4(0.f, 0.f, 0.f, 0.f);
    float4 q = make_float4(0.f, 0.f, 0.f, 0.f);
#pragma unroll
    for (int j = 0; j < 8; ++j) {
      int i = blk * 256 + t + j * 262144;
      float4 v = in[i];
      s.x += v.x; s.y += v.y; s.z += v.z; s.w += v.w;
      q.x += v.x * v.x; q.y += v.y * v.y; q.z += v.z * v.z; q.w += v.w * v.w;
      u16x4 o;
      o[0] = f2bf(v.x); o[1] = f2bf(v.y); o[2] = f2bf(v.z); o[3] = f2bf(v.w);
      out[i] = o;
    }
    ((float4*)(psB + (size_t)blk * DIM))[t] = s;
    ((float4*)(pqB + (size_t)blk * DIM))[t] = q;
    return;
  }
  for (int i = blockIdx.x * 256 + threadIdx.x; i < n4; i += gridDim.x * 256) {
    float4 v = in[i];
    u16x4 o;
    o[0] = f2bf(v.x); o[1] = f2bf(v.y); o[2] = f2bf(v.z); o[3] = f2bf(v.w);
    out[i] = o;
  }
}

// transpose-convert 4x 1024x1024 f32 W -> bf16 WT[n][k] = W[k][n]
__global__ __launch_bounds__(256) void wtrans4_kernel(
    const float* __restrict__ W0, const float* __restrict__ W1,
    const float* __restrict__ W2, const float* __restrict__ W3,
    u16* __restrict__ T0, u16* __restrict__ T1, u16* __restrict__ T2, u16* __restrict__ T3) {
  const float* W = (blockIdx.z == 0) ? W0 : (blockIdx.z == 1) ? W1 : (blockIdx.z == 2) ? W2 : W3;
  u16* WT = (blockIdx.z == 0) ? T0 : (blockIdx.z == 1) ? T1 : (blockIdx.z == 2) ? T2 : T3;
  __shared__ float tile[64][65];
  const int t = threadIdx.x;
  const int kb = blockIdx.x * 64, nb = blockIdx.y * 64;
#pragma unroll
  for (int i = 0; i < 16; ++i) {
    int r = i * 4 + (t >> 6), c = t & 63;
    tile[c][r] = W[(size_t)(kb + r) * 1024 + nb + c];
  }
  __syncthreads();
#pragma unroll
  for (int i = 0; i < 16; ++i) {
    int n = i * 4 + (t >> 6), kk = t & 63;
    WT[(size_t)(nb + n) * 1024 + kb + kk] = f2bf(tile[n][kk]);
  }
}

// ---------------- 128x128 bf16 MFMA GEMM (fallback only) ----------------

#define TM 128
#define TN 128
#define TK 32

template <int OUT>
__global__ __launch_bounds__(256) void bgemm_kernel(
    const u16* __restrict__ A, const u16* __restrict__ Bt, void* __restrict__ C,
    const float* __restrict__ bias, int M, int N, int K, int ldc, float alpha) {
  __shared__ __align__(16) u16 As[TM * TK];
  __shared__ __align__(16) u16 Bs[TN * TK];

  const int t = threadIdx.x;
  const int l = t & 63;
  const int w = t >> 6;
  const int wm = w >> 1, wn = w & 1;
  const size_t row0 = (size_t)blockIdx.y * TM;
  const size_t col0 = (size_t)blockIdx.x * TN;

  f32x4 acc[4][4];
#pragma unroll
  for (int m = 0; m < 4; ++m)
#pragma unroll
    for (int n = 0; n < 4; ++n) acc[m][n] = (f32x4){0.f, 0.f, 0.f, 0.f};

  const int lane_r = l & 15;
  const int kgrp = (l >> 4) * 8;

  for (int k0 = 0; k0 < K; k0 += TK) {
#pragma unroll
    for (int j = 0; j < 2; ++j) {
      int idx = j * 256 + t;
      int r = idx >> 2, c8 = (idx & 3) << 3;
      __builtin_amdgcn_global_load_lds((gu32*)(A + (row0 + r) * K + k0 + c8),
                                       (lu32*)(As + idx * 8), 16, 0, 0);
      __builtin_amdgcn_global_load_lds((gu32*)(Bt + (col0 + r) * K + k0 + c8),
                                       (lu32*)(Bs + idx * 8), 16, 0, 0);
    }
    __syncthreads();

    short8 a[4], b[4];
#pragma unroll
    for (int m = 0; m < 4; ++m)
      a[m] = *(const short8*)&As[(wm * 64 + m * 16 + lane_r) * TK + kgrp];
#pragma unroll
    for (int n = 0; n < 4; ++n)
      b[n] = *(const short8*)&Bs[(wn * 64 + n * 16 + lane_r) * TK + kgrp];
#pragma unroll
    for (int m = 0; m < 4; ++m)
#pragma unroll
      for (int n = 0; n < 4; ++n)
        acc[m][n] = __builtin_amdgcn_mfma_f32_16x16x32_bf16(a[m], b[n], acc[m][n], 0, 0, 0);
    __syncthreads();
  }

#pragma unroll
  for (int m = 0; m < 4; ++m) {
#pragma unroll
    for (int n = 0; n < 4; ++n) {
      size_t col = col0 + wn * 64 + n * 16 + lane_r;
      size_t rbase = row0 + wm * 64 + m * 16 + (l >> 4) * 4;
      if (OUT == 0) {
        float bv = bias[col];
#pragma unroll
        for (int j = 0; j < 4; ++j)
          ((float*)C)[(rbase + j) * (size_t)ldc + col] = acc[m][n][j] * alpha + bv;
      } else if (OUT == 1) {
#pragma unroll
        for (int j = 0; j < 4; ++j)
          ((u16*)C)[(rbase + j) * (size_t)ldc + col] = f2bf(acc[m][n][j] * alpha);
      } else {
        u16x4 p;
#pragma unroll
        for (int j = 0; j < 4; ++j) p[j] = f2bf(acc[m][n][j] * alpha);
        *(u16x4*)&((u16*)C)[col * (size_t)ldc + rbase] = p;
      }
    }
  }
}

// ---------------- shared GEMM macros (256^2, 8 waves, BK=64) ----------------

template <int VM>
__device__ __forceinline__ void waitvm() {
  if constexpr (VM == 4) asm volatile("s_waitcnt vmcnt(4)" ::: "memory");
  else asm volatile("s_waitcnt vmcnt(0)" ::: "memory");
}
#define FENCE asm volatile("" ::: "memory")
#define BARRIER do { FENCE; __builtin_amdgcn_s_barrier(); FENCE; } while (0)

#define SGA(UNIT, KT, BUF)                                                          \
  __builtin_amdgcn_global_load_lds(                                                 \
      (gu32*)(Agp + (size_t)((UNIT) * 64) * ldaB + (size_t)(KT) * 128),             \
      (lu32*)(smem + (BUF) * 16384 + (UNIT) * 4096 + tid * 8), 16, 0, 0)

#define SGB(UNIT, KT, BUF)                                                          \
  do {                                                                              \
    int _rp = (UNIT) * 64 + rr;                                                     \
    size_t _row = (size_t)(bn0 + ((_rp >> 5) & 3) * 64 + (_rp >> 7) * 32 + (_rp & 31)); \
    __builtin_amdgcn_global_load_lds(                                               \
        (gu32*)(Bgp + _row * ldbB + (size_t)(KT) * 128),                            \
        (lu32*)(smem + 32768 + (BUF) * 16384 + (UNIT) * 4096 + tid * 8), 16, 0, 0); \
  } while (0)

#define RDA4(DST, BO, MQ, KO)                                                       \
  _Pragma("unroll") for (int fr = 0; fr < 4; ++fr)                                  \
    DST[fr] = *(const short8*)(smemc + (BO) + aRd + (MQ) * 8192 + fr * 2048 + (KO));

#define RDB2(NQ_, KK, BO, KO)                                                       \
  _Pragma("unroll") for (int fc = 0; fc < 2; ++fc)                                  \
    bf[NQ_][KK][fc] = *(const short8*)(smemc + 65536 + (BO) + bRd + (NQ_) * 16384 + fc * 2048 + (KO));

#define MM8(AF, MQ, NQ_, KK)                                                        \
  do {                                                                              \
    __builtin_amdgcn_s_setprio(1);                                                  \
    _Pragma("unroll") for (int fr = 0; fr < 4; ++fr)                                \
    _Pragma("unroll") for (int fc = 0; fc < 2; ++fc)                                \
      acc[(MQ) * 4 + fr][(NQ_) * 2 + fc] = __builtin_amdgcn_mfma_f32_16x16x32_bf16( \
          AF[fr], bf[NQ_][KK][fc], acc[(MQ) * 4 + fr][(NQ_) * 2 + fc], 0, 0, 0);    \
    __builtin_amdgcn_s_setprio(0);                                                  \
  } while (0)

#define GEMM_SETUP                                                                  \
  __shared__ __align__(16) u16 smem[65536];                                         \
  const char* smemc = (const char*)smem;                                            \
  const int tid = threadIdx.x;                                                      \
  const int l = tid & 63;                                                           \
  const int wid = tid >> 6;                                                         \
  const int wm = wid >> 2, wn = wid & 3;                                            \
  const int lane_r = l & 15;                                                        \
  const int kq = l >> 4;                                                            \
  const int rr = tid >> 3;                                                          \
  const int bid = blockIdx.x;                                                       \
  const int xcd = bid & 7;                                                          \
  const int c = bid >> 3;                                                           \
  const int tm = xcd * tmb + (c % tmb);                                             \
  const int tn = c / tmb;                                                           \
  const int am0 = tm * 256, bn0 = tn * 256;                                         \
  const size_t kglob = kspanB * blockIdx.y;                                         \
  const int kx = (lane_r & 7) << 4;                                                 \
  const int koff0 = (kq << 4) ^ kx;                                                 \
  const int koff1 = (64 | (kq << 4)) ^ kx;                                          \
  const int aRd = (wm * 128 + lane_r) * 128;                                        \
  const int bRd = (wn * 32 + lane_r) * 128;                                         \
  const int scol = ((tid & 7) ^ ((tid >> 3) & 7)) << 4;                             \
  const char* Agp = (const char*)A + (size_t)(am0 + rr) * ldaB + kglob + scol;      \
  const char* Bgp = (const char*)Bt + kglob + scol;                                 \
  f32x4 acc[8][4];                                                                  \
  _Pragma("unroll") for (int i = 0; i < 8; ++i)                                     \
  _Pragma("unroll") for (int j = 0; j < 4; ++j) acc[i][j] = (f32x4){0.f, 0.f, 0.f, 0.f};

// ---------------- R5-schedule 256^2 kernel (all GEMMs) ----------------
// OUT: 0 = bf16 store; 1 = bf16 split-K partial at C + cstride*blockIdx.y;
//      2 = fused qkv projection (band by am0>>13: Wq/Wk/Wv -> qh/kh/vhT^T);
//      3 = f32 store + bias (out-projection);
//      4 = QK^T fused bias+exp epilogue (no-max softmax; pre-scaled centers)

template <int OUT>
__global__ __launch_bounds__(512, 2) void gemm256_kernel(
    const u16* __restrict__ A, const u16* __restrict__ Bt, void* __restrict__ C,
    const float* __restrict__ bias, const float2* __restrict__ cqp,
    const float2* __restrict__ crp, const float* __restrict__ bwp,
    float* __restrict__ psum, int NT, int nTn, int tmb,
    size_t ldaB, size_t ldbB, int ldc, size_t kspanB, size_t cstride, float alpha) {
  GEMM_SETUP;

  int band = 0;
  const u16* Bt2 = Bt;
  if (OUT == 2) { band = am0 >> 13; Bt2 = Bt + ((size_t)band << 20); }
  const char* Bgp2 = (const char*)Bt2 + kglob + scol;
  #define Bgp Bgp2

  short8 afP[4], afQ[4], bf[2][2][2];

  // prologue: tile0 -> buf0 (early-consumed units first)
  SGA(0, 0, 0); SGA(2, 0, 0); SGB(0, 0, 0); SGB(1, 0, 0);
  SGB(2, 0, 0); SGB(3, 0, 0); SGA(1, 0, 0); SGA(3, 0, 0);
  waitvm<0>();
  BARRIER;
  RDA4(afP, 0, 0, koff0);
  RDB2(0, 0, 0, koff0);

  for (int t = 0; t < NT; ++t) {
    const int bo = (t & 1) * 32768;
    const int nbo = bo ^ 32768;
    const int nb = (t & 1) ^ 1;
    const bool more = (t + 1 < NT);
    if (more) { SGA(0, t + 1, nb); SGA(2, t + 1, nb); }
    RDB2(1, 0, bo, koff0);
    MM8(afP, 0, 0, 0);
    if (more) { SGB(0, t + 1, nb); SGB(1, t + 1, nb); }
    RDA4(afQ, bo, 1, koff0);
    MM8(afP, 0, 1, 0);
    if (more) { SGB(2, t + 1, nb); SGB(3, t + 1, nb); }
    RDB2(0, 1, bo, koff1);
    MM8(afQ, 1, 1, 0);
    if (more) { SGA(1, t + 1, nb); SGA(3, t + 1, nb); }
    RDA4(afP, bo, 1, koff1);
    MM8(afQ, 1, 0, 0);
    RDB2(1, 1, bo, koff1);
    MM8(afP, 1, 0, 1);
    RDA4(afQ, bo, 0, koff1);
    MM8(afP, 1, 1, 1);
    MM8(afQ, 0, 1, 1);
    waitvm<4>();
    BARRIER;
    if (more) { RDA4(afP, nbo, 0, koff0); RDB2(0, 0, nbo, koff0); }
    MM8(afQ, 0, 0, 1);
    waitvm<0>();
    BARRIER;
  }
  #undef Bgp

  // ---------------- epilogue (16x16x32 C layout: col = lane&15, row = kq*4+j) ----
  if (OUT == 4) {
    const float sc = bwp[0] * 1.44269504f;
    const float eps2 = sc * sc * 1e-8f;
    float* psld = (float*)smem;
    float2 crv[4];
#pragma unroll
    for (int fc2 = 0; fc2 < 4; ++fc2) crv[fc2] = crp[bn0 + wn * 64 + fc2 * 16 + lane_r];
#pragma unroll
    for (int fp = 0; fp < 8; ++fp) {
      float rs[4] = {0.f, 0.f, 0.f, 0.f};
      int rbase = am0 + wm * 128 + fp * 16 + kq * 4;
#pragma unroll
      for (int j = 0; j < 4; ++j) {
        float2 cqv = cqp[rbase + j];
#pragma unroll
        for (int fc2 = 0; fc2 < 4; ++fc2) {
          float dx = cqv.x - crv[fc2].x, dy = cqv.y - crv[fc2].y;
          float d2v = fmaf(dx, dx, fmaf(dy, dy, eps2));
          float D;
          asm("v_sqrt_f32 %0, %1" : "=v"(D) : "v"(d2v));
          float l2 = fmaf(acc[fp][fc2][j], 1.44269504f, -D);
          float pv;
          asm("v_exp_f32 %0, %1" : "=v"(pv) : "v"(l2));
          rs[j] += pv;
          int col = bn0 + wn * 64 + fc2 * 16 + lane_r;
          ((u16*)C)[(size_t)(rbase + j) * ldc + col] = f2bf(pv);
        }
      }
#pragma unroll
      for (int j = 0; j < 4; ++j) {
        float s = rs[j];
        s += __shfl_xor(s, 1); s += __shfl_xor(s, 2);
        s += __shfl_xor(s, 4); s += __shfl_xor(s, 8);
        if (lane_r == 0)
          psld[(wm * 128 + fp * 16 + kq * 4 + j) * 4 + wn] = s;
      }
    }
    __syncthreads();
    if (tid < 256) {
      float s = psld[tid * 4] + psld[tid * 4 + 1] + psld[tid * 4 + 2] + psld[tid * 4 + 3];
      psum[(size_t)tn * NQ + am0 + tid] = s;
    }
    return;
  }
#pragma unroll
  for (int fp = 0; fp < 8; ++fp) {
#pragma unroll
    for (int fc2 = 0; fc2 < 4; ++fc2) {
      int row = am0 + wm * 128 + fp * 16 + kq * 4;
      int col = bn0 + wn * 64 + fc2 * 16 + lane_r;
      if (OUT == 0) {
#pragma unroll
        for (int j = 0; j < 4; ++j)
          ((u16*)C)[(size_t)(row + j) * ldc + col] = f2bf(acc[fp][fc2][j] * alpha);
      } else if (OUT == 1) {
        u16* Cp = (u16*)C + cstride * blockIdx.y;
#pragma unroll
        for (int j = 0; j < 4; ++j)
          Cp[(size_t)(row + j) * ldc + col] = f2bf(acc[fp][fc2][j]);
      } else if (OUT == 3) {
        float* Cf = (float*)C;
        float bv = bias[col];
#pragma unroll
        for (int j = 0; j < 4; ++j)
          Cf[(size_t)(row + j) * ldc + col] = acc[fp][fc2][j] * alpha + bv;
      } else {
        int arow = row & 8191;
        if (band < 2) {
          u16* D = (u16*)C + ((size_t)band << 23);  // qh / kh
          float a2 = (band == 0) ? 0.03125f : 1.f;
#pragma unroll
          for (int j = 0; j < 4; ++j)
            D[(size_t)(arow + j) * DIM + col] = f2bf(acc[fp][fc2][j] * a2);
        } else {
          u16* D = (u16*)C + ((size_t)2 << 23);     // vhT (transposed)
          u16x4 pk;
#pragma unroll
          for (int j = 0; j < 4; ++j) pk[j] = f2bf(acc[fp][fc2][j]);
          *(u16x4*)&D[(size_t)col * NK + arow] = pk;
        }
      }
    }
  }
}

// ---------------- row-sum inverse: inv[r] = 1 / sum_t psum[t][r] ----------------

__global__ void rowinv_kernel(const float* __restrict__ psum, float* __restrict__ inv) {
  int r = blockIdx.x * 256 + threadIdx.x;
  float s = 0.f;
#pragma unroll
  for (int t = 0; t < 32; ++t) s += psum[(size_t)t * NQ + r];
  inv[r] = 1.f / s;
}

// ---------------- split-K=2 combine with row normalization ----------------

__global__ void combine2_kernel(const u16x8* __restrict__ p, const float* __restrict__ inv,
                                u16x8* __restrict__ out) {
  const size_t st = (size_t)NQ * DIM / 8;
  size_t i = (size_t)blockIdx.x * 256 + threadIdx.x;
  u16x8 a = p[i], b = p[i + st];
  float iv = inv[i >> 7];
  u16x8 o;
#pragma unroll
  for (int j = 0; j < 8; ++j)
    o[j] = f2bf((bf2f(a[j]) + bf2f(b[j])) * iv);
  out[i] = o;
}

// ---------------- fused bias + row softmax, bf16 in place (fallback path) --------

__global__ __launch_bounds__(256) void softmax_bias_bf16_kernel(
    u16* __restrict__ S, const float2* __restrict__ cq, const float2* __restrict__ cr,
    const float* __restrict__ bwp, int qr0) {
  __shared__ float red[256];
  const int t = threadIdx.x;
  u16* row = S + (size_t)blockIdx.x * NK;
  const float2 cqv = cq[qr0 + blockIdx.x];
  const float bw = bwp[0];

  float l[32];
  float mx = -1e30f;
#pragma unroll
  for (int i = 0; i < 4; ++i) {
    int base = (i * 256 + t) * 8;
    u16x8 u = *(const u16x8*)&row[base];
#pragma unroll
    for (int j = 0; j < 8; ++j) {
      float x = bf2f(u[j]);
      float2 c = cr[base + j];
      float dx = cqv.x - c.x, dy = cqv.y - c.y;
      float lv = x - bw * sqrtf(dx * dx + dy * dy + 1e-8f);
      l[i * 8 + j] = lv;
      mx = fmaxf(mx, lv);
    }
  }
  red[t] = mx; __syncthreads();
  for (int s = 128; s > 0; s >>= 1) { if (t < s) red[t] = fmaxf(red[t], red[t + s]); __syncthreads(); }
  mx = red[0]; __syncthreads();

  float sum = 0.f;
#pragma unroll
  for (int i = 0; i < 32; ++i) { float e = __expf(l[i] - mx); l[i] = e; sum += e; }
  red[t] = sum; __syncthreads();
  for (int s = 128; s > 0; s >>= 1) { if (t < s) red[t] += red[t + s]; __syncthreads(); }
  float inv = 1.f / red[0];

#pragma unroll
  for (int i = 0; i < 4; ++i) {
    int base = (i * 256 + t) * 8;
    u16x8 o;
#pragma unroll
    for (int j = 0; j < 8; ++j) o[j] = f2bf(l[i * 8 + j] * inv);
    *(u16x8*)&row[base] = o;
  }
}

// ---------------- host ----------------

extern "C" void kernel_launch(void* const* d_in, const int* in_sizes, int n_in,
                              void* d_out, int out_size, void* d_ws, size_t ws_size,
                              hipStream_t stream) {
  const float* q  = (const float*)d_in[0];
  const float* k  = (const float*)d_in[1];
  const float* v  = (const float*)d_in[2];
  const float* rb = (const float*)d_in[3];
  const float* qb = (const float*)d_in[4];
  const float* Wq = (const float*)d_in[5];
  const float* Wk = (const float*)d_in[6];
  const float* Wv = (const float*)d_in[7];
  const float* Wp = (const float*)d_in[8];
  const float* bp = (const float*)d_in[9];
  const float* W1 = (const float*)d_in[10];
  const float* b1 = (const float*)d_in[11];
  const float* W2 = (const float*)d_in[12];
  const float* b2 = (const float*)d_in[13];
  float* out = (float*)d_out;

  // qbf|kbf dead after proj -> hold the two 16 MB bf16 split-K partials of PV.
  char* p = (char*)d_ws;
  const size_t PROJB = (size_t)NQ * DIM * sizeof(u16);  // 16 MB
  u16* qbf = (u16*)p;            p += PROJB;
  u16* kbf = (u16*)p;            p += PROJB;
  u16* vbf = (u16*)p;            p += PROJB;
  u16* qh  = (u16*)p;            p += PROJB;
  u16* kh  = (u16*)p;            p += PROJB;
  u16* vhT = (u16*)p;            p += PROJB;
  u16* WqT = (u16*)p;            p += (size_t)DIM * DIM * 2;
  u16* WkT = (u16*)p;            p += (size_t)DIM * DIM * 2;
  u16* WvT = (u16*)p;            p += (size_t)DIM * DIM * 2;
  u16* WpT = (u16*)p;            p += (size_t)DIM * DIM * 2;
  float* cq  = (float*)p;        p += 2 * NQ * 4;
  float* cr  = (float*)p;        p += 2 * NK * 4;
  float* cqs = (float*)p;        p += 2 * NQ * 4;
  float* crs = (float*)p;        p += 2 * NK * 4;
  float* ps  = (float*)p;        p += 32 * DIM * 4;   // fallback var partials
  float* pq  = (float*)p;        p += 32 * DIM * 4;
  float* gfv = (float*)p;        p += DIM * 4;
  float* h1p = (float*)p;        p += 8 * 2048 * 4;
  float* bw  = (float*)p;        p += 64;
  float* psum = (float*)p;       p += (size_t)32 * NQ * 4;
  float* rinv = (float*)p;       p += (size_t)NQ * 4;
  size_t fixed_b = (size_t)(p - (char*)d_ws);

  int SR = 256;
  for (int cand = 8192; cand >= 256; cand >>= 1) {
    if (fixed_b + (size_t)cand * (NK + DIM) * 2 <= ws_size) { SR = cand; break; }
  }
  u16* Sbuf = (u16*)p;
  u16* Obuf = Sbuf + (size_t)SR * NK;

  const int N4 = NQ * DIM / 4;

  if (SR == 8192) {
    // var partials fused into f2bf3's k-branch; partials live in the (not yet
    // written) Sbuf region: psB[1024][1024] + pqB[1024][1024] = 8 MB.
    float* psB = (float*)Sbuf;
    float* pqB = psB + (size_t)1024 * DIM;
    f2bf3_kernel<<<dim3(1024, 3), 256, 0, stream>>>(
        (const float4*)q, (const float4*)k, (const float4*)v,
        (u16x4*)qbf, (u16x4*)kbf, (u16x4*)vbf, N4, psB, pqB);
    gfv_kernel<<<4, 256, 0, stream>>>(psB, pqB, gfv, 1024);
  } else {
    f2bf3_kernel<<<dim3(1024, 3), 256, 0, stream>>>(
        (const float4*)q, (const float4*)k, (const float4*)v,
        (u16x4*)qbf, (u16x4*)kbf, (u16x4*)vbf, N4, nullptr, nullptr);
    var_partial_kernel<<<dim3(4, 32), 256, 0, stream>>>(k, ps, pq);
    gfv_kernel<<<4, 256, 0, stream>>>(ps, pq, gfv, 32);
  }
  h1_partial_kernel<<<dim3(8, 8), 256, 0, stream>>>(gfv, W1, h1p);
  bw_kernel<<<1, 256, 0, stream>>>(h1p, b1, W2, b2, bw);
  centers_kernel<<<32, 256, 0, stream>>>((const float4*)qb, (const float4*)rb, bw,
                                         (float2*)cq, (float2*)cr,
                                         (float2*)cqs, (float2*)crs);
  wtrans4_kernel<<<dim3(16, 16, 4), 256, 0, stream>>>(Wq, Wk, Wv, Wp, WqT, WkT, WvT, WpT);

  // fused q/k/v projections (R5 schedule)
  gemm256_kernel<2><<<dim3(384, 1), 512, 0, stream>>>(
      qbf, WqT, qh, nullptr, nullptr, nullptr, nullptr, nullptr,
      16, 4, 12, 2048, 2048, DIM, 0, 0, 1.f);

  if (SR == 8192) {
    // S = exp(qh @ kh^T - bw*dist) fused (scaled centers); row sums -> psum
    // (overwrites the psB/pqB scratch — var chain already consumed it)
    gemm256_kernel<4><<<dim3(1024, 1), 512, 0, stream>>>(
        qh, kh, Sbuf, nullptr, (const float2*)cqs, (const float2*)crs, bw, psum,
        16, 32, 4, 2048, 2048, NK, 0, 0, 1.f);
    rowinv_kernel<<<32, 256, 0, stream>>>(psum, rinv);
    // O' = P' @ vh, split-K=2 (256 blocks = 1/CU, NT=64), bf16 partials in qbf|kbf
    gemm256_kernel<1><<<dim3(128, 2), 512, 0, stream>>>(
        Sbuf, vhT, qbf, nullptr, nullptr, nullptr, nullptr, nullptr,
        64, 4, 4, 16384, 16384, DIM, 8192, (size_t)NQ * DIM, 1.f);
    combine2_kernel<<<4096, 256, 0, stream>>>((const u16x8*)qbf, rinv, (u16x8*)Obuf);
    // out = O @ Wp + bp
    gemm256_kernel<3><<<dim3(128, 1), 512, 0, stream>>>(
        Obuf, WpT, out, bp, nullptr, nullptr, nullptr, nullptr,
        16, 4, 4, 2048, 2048, DIM, 0, 0, 1.f);
  } else {
    for (int s0 = 0; s0 < NQ; s0 += SR) {
      bgemm_kernel<1><<<dim3(NK / TN, SR / TM), 256, 0, stream>>>(
          qh + (size_t)s0 * DIM, kh, Sbuf, nullptr, SR, NK, DIM, NK, 1.f);
      softmax_bias_bf16_kernel<<<SR, 256, 0, stream>>>(
          Sbuf, (const float2*)cq, (const float2*)cr, bw, s0);
      bgemm_kernel<1><<<dim3(DIM / TN, SR / TM), 256, 0, stream>>>(
          Sbuf, vhT, Obuf, nullptr, SR, DIM, NK, DIM, 1.f);
      bgemm_kernel<0><<<dim3(DIM / TN, SR / TM), 256, 0, stream>>>(
          Obuf, WpT, out + (size_t)s0 * DIM, bp, SR, DIM, DIM, DIM, 1.f);
    }
  }
}

// Round 13
// 408.091 us; speedup vs baseline: 1.5870x; 1.5870x over previous
//
#include <hip/hip_runtime.h>
#include <math.h>

#define DIM 1024
#define NQ 8192
#define NK 8192

typedef unsigned short u16;
typedef __attribute__((ext_vector_type(8))) short short8;
typedef __attribute__((ext_vector_type(8))) u16 u16x8;
typedef __attribute__((ext_vector_type(4))) u16 u16x4;
typedef __attribute__((ext_vector_type(4))) float f32x4;
typedef __attribute__((address_space(1))) const unsigned int gu32;
typedef __attribute__((address_space(3))) unsigned int lu32;

__device__ inline u16 f2bf(float f) {
  unsigned u = __builtin_bit_cast(unsigned, f);
  u += 0x7fff + ((u >> 16) & 1);
  return (u16)(u >> 16);
}
__device__ inline float bf2f(u16 h) {
  unsigned u = ((unsigned)h) << 16;
  return __builtin_bit_cast(float, u);
}

// ---------------- small kernels: var -> MLP -> bias_weight ----------------

// fallback-only separate var pass
__global__ void var_partial_kernel(const float* __restrict__ k,
                                   float* __restrict__ ps, float* __restrict__ pq) {
  int col = blockIdx.x * 256 + threadIdx.x;
  int r0  = blockIdx.y * 256;
  float s = 0.f, q = 0.f;
  for (int r = 0; r < 256; ++r) {
    float x = k[(size_t)(r0 + r) * DIM + col];
    s += x; q += x * x;
  }
  ps[blockIdx.y * DIM + col] = s;
  pq[blockIdx.y * DIM + col] = q;
}

__global__ void gfv_kernel(const float* __restrict__ ps, const float* __restrict__ pq,
                           float* __restrict__ gfv, int np) {
  int col = blockIdx.x * 256 + threadIdx.x;
  float s = 0.f, q = 0.f;
  for (int c = 0; c < np; ++c) { s += ps[(size_t)c * DIM + col]; q += pq[(size_t)c * DIM + col]; }
  const float n = 8192.f;
  gfv[col] = (q - s * s / n) / (n - 1.f);  // unbiased var (ddof=1)
}

// hierarchical reduction of 1024x1024 partials (fused-var path).
// block b: 32 cols (lane-adjacent, coalesced), 8 row-groups x 128 rows, LDS reduce.
__global__ __launch_bounds__(256) void var_reduce_kernel(
    const float* __restrict__ psB, const float* __restrict__ pqB,
    float* __restrict__ gfv) {
  __shared__ float sred[8][33], qred[8][33];
  const int t = threadIdx.x;
  const int cl = t & 31;
  const int rg = t >> 5;
  const int col = blockIdx.x * 32 + cl;
  float s = 0.f, q = 0.f;
  for (int r = rg * 128; r < rg * 128 + 128; ++r) {
    s += psB[(size_t)r * DIM + col];
    q += pqB[(size_t)r * DIM + col];
  }
  sred[rg][cl] = s; qred[rg][cl] = q;
  __syncthreads();
  if (rg == 0) {
#pragma unroll
    for (int g = 1; g < 8; ++g) { s += sred[g][cl]; q += qred[g][cl]; }
    const float n = 8192.f;
    gfv[col] = (q - s * s / n) / (n - 1.f);
  }
}

__global__ void h1_partial_kernel(const float* __restrict__ gfv, const float* __restrict__ W1,
                                  float* __restrict__ h1p) {
  int j  = blockIdx.x * 256 + threadIdx.x;
  int d0 = blockIdx.y * 128;
  float acc = 0.f;
  for (int d = 0; d < 128; ++d)
    acc += gfv[d0 + d] * W1[(size_t)(d0 + d) * 2048 + j];
  h1p[blockIdx.y * 2048 + j] = acc;
}

__global__ void bw_kernel(const float* __restrict__ h1p, const float* __restrict__ b1,
                          const float* __restrict__ W2, const float* __restrict__ b2,
                          float* __restrict__ bw) {
  __shared__ float red[256];
  int t = threadIdx.x;
  float acc = 0.f;
  for (int i = 0; i < 8; ++i) {
    int j = i * 256 + t;
    float h = b1[j];
    for (int c = 0; c < 8; ++c) h += h1p[c * 2048 + j];
    h = fmaxf(h, 0.f);
    acc += h * W2[j];
  }
  red[t] = acc; __syncthreads();
  for (int s = 128; s > 0; s >>= 1) { if (t < s) red[t] += red[t + s]; __syncthreads(); }
  if (t == 0) bw[0] = 1.f / (1.f + __expf(-(red[0] + b2[0])));
}

// centers: unscaled (cq,cr for fallback) + scaled by bw*log2e (cqs,crs for fused path)
__global__ void centers_kernel(const float4* __restrict__ qb, const float4* __restrict__ rb,
                               const float* __restrict__ bwp,
                               float2* __restrict__ cq, float2* __restrict__ cr,
                               float2* __restrict__ cqs, float2* __restrict__ crs) {
  int i = blockIdx.x * 256 + threadIdx.x;
  const float sc = bwp[0] * 1.44269504f;
  float4 a = qb[i];
  float2 c1 = make_float2(0.5f * (a.x + a.z), 0.5f * (a.y + a.w));
  cq[i] = c1;
  cqs[i] = make_float2(c1.x * sc, c1.y * sc);
  float4 b = rb[i];
  float2 c2 = make_float2(0.5f * (b.x + b.z), 0.5f * (b.y + b.w));
  cr[i] = c2;
  crs[i] = make_float2(c2.x * sc, c2.y * sc);
}

// ---------------- conversion kernels (fused launches) ----------------
// y==1 (k) branch fuses var partial sums: thread (b,t) covers
// rows {b, b+1024, ..., b+7168} x cols {4t..4t+3} -> psB[b][4t..4t+3].

__global__ void f2bf3_kernel(const float4* __restrict__ a, const float4* __restrict__ b,
                             const float4* __restrict__ c, u16x4* __restrict__ oa,
                             u16x4* __restrict__ ob, u16x4* __restrict__ oc, int n4,
                             float* __restrict__ psB, float* __restrict__ pqB) {
  const float4* in = (blockIdx.y == 0) ? a : (blockIdx.y == 1) ? b : c;
  u16x4* out = (blockIdx.y == 0) ? oa : (blockIdx.y == 1) ? ob : oc;
  if (blockIdx.y == 1 && psB) {
    const int t = threadIdx.x, blk = blockIdx.x;
    float4 s = make_float4(0.f, 0.f, 0.f, 0.f);
    float4 q = make_float4(0.f, 0.f, 0.f, 0.f);
#pragma unroll
    for (int j = 0; j < 8; ++j) {
      int i = blk * 256 + t + j * 262144;
      float4 v = in[i];
      s.x += v.x; s.y += v.y; s.z += v.z; s.w += v.w;
      q.x += v.x * v.x; q.y += v.y * v.y; q.z += v.z * v.z; q.w += v.w * v.w;
      u16x4 o;
      o[0] = f2bf(v.x); o[1] = f2bf(v.y); o[2] = f2bf(v.z); o[3] = f2bf(v.w);
      out[i] = o;
    }
    ((float4*)(psB + (size_t)blk * DIM))[t] = s;
    ((float4*)(pqB + (size_t)blk * DIM))[t] = q;
    return;
  }
  for (int i = blockIdx.x * 256 + threadIdx.x; i < n4; i += gridDim.x * 256) {
    float4 v = in[i];
    u16x4 o;
    o[0] = f2bf(v.x); o[1] = f2bf(v.y); o[2] = f2bf(v.z); o[3] = f2bf(v.w);
    out[i] = o;
  }
}

// transpose-convert 4x 1024x1024 f32 W -> bf16 WT[n][k] = W[k][n]
__global__ __launch_bounds__(256) void wtrans4_kernel(
    const float* __restrict__ W0, const float* __restrict__ W1,
    const float* __restrict__ W2, const float* __restrict__ W3,
    u16* __restrict__ T0, u16* __restrict__ T1, u16* __restrict__ T2, u16* __restrict__ T3) {
  const float* W = (blockIdx.z == 0) ? W0 : (blockIdx.z == 1) ? W1 : (blockIdx.z == 2) ? W2 : W3;
  u16* WT = (blockIdx.z == 0) ? T0 : (blockIdx.z == 1) ? T1 : (blockIdx.z == 2) ? T2 : T3;
  __shared__ float tile[64][65];
  const int t = threadIdx.x;
  const int kb = blockIdx.x * 64, nb = blockIdx.y * 64;
#pragma unroll
  for (int i = 0; i < 16; ++i) {
    int r = i * 4 + (t >> 6), c = t & 63;
    tile[c][r] = W[(size_t)(kb + r) * 1024 + nb + c];
  }
  __syncthreads();
#pragma unroll
  for (int i = 0; i < 16; ++i) {
    int n = i * 4 + (t >> 6), kk = t & 63;
    WT[(size_t)(nb + n) * 1024 + kb + kk] = f2bf(tile[n][kk]);
  }
}

// ---------------- 128x128 bf16 MFMA GEMM (fallback only) ----------------

#define TM 128
#define TN 128
#define TK 32

template <int OUT>
__global__ __launch_bounds__(256) void bgemm_kernel(
    const u16* __restrict__ A, const u16* __restrict__ Bt, void* __restrict__ C,
    const float* __restrict__ bias, int M, int N, int K, int ldc, float alpha) {
  __shared__ __align__(16) u16 As[TM * TK];
  __shared__ __align__(16) u16 Bs[TN * TK];

  const int t = threadIdx.x;
  const int l = t & 63;
  const int w = t >> 6;
  const int wm = w >> 1, wn = w & 1;
  const size_t row0 = (size_t)blockIdx.y * TM;
  const size_t col0 = (size_t)blockIdx.x * TN;

  f32x4 acc[4][4];
#pragma unroll
  for (int m = 0; m < 4; ++m)
#pragma unroll
    for (int n = 0; n < 4; ++n) acc[m][n] = (f32x4){0.f, 0.f, 0.f, 0.f};

  const int lane_r = l & 15;
  const int kgrp = (l >> 4) * 8;

  for (int k0 = 0; k0 < K; k0 += TK) {
#pragma unroll
    for (int j = 0; j < 2; ++j) {
      int idx = j * 256 + t;
      int r = idx >> 2, c8 = (idx & 3) << 3;
      __builtin_amdgcn_global_load_lds((gu32*)(A + (row0 + r) * K + k0 + c8),
                                       (lu32*)(As + idx * 8), 16, 0, 0);
      __builtin_amdgcn_global_load_lds((gu32*)(Bt + (col0 + r) * K + k0 + c8),
                                       (lu32*)(Bs + idx * 8), 16, 0, 0);
    }
    __syncthreads();

    short8 a[4], b[4];
#pragma unroll
    for (int m = 0; m < 4; ++m)
      a[m] = *(const short8*)&As[(wm * 64 + m * 16 + lane_r) * TK + kgrp];
#pragma unroll
    for (int n = 0; n < 4; ++n)
      b[n] = *(const short8*)&Bs[(wn * 64 + n * 16 + lane_r) * TK + kgrp];
#pragma unroll
    for (int m = 0; m < 4; ++m)
#pragma unroll
      for (int n = 0; n < 4; ++n)
        acc[m][n] = __builtin_amdgcn_mfma_f32_16x16x32_bf16(a[m], b[n], acc[m][n], 0, 0, 0);
    __syncthreads();
  }

#pragma unroll
  for (int m = 0; m < 4; ++m) {
#pragma unroll
    for (int n = 0; n < 4; ++n) {
      size_t col = col0 + wn * 64 + n * 16 + lane_r;
      size_t rbase = row0 + wm * 64 + m * 16 + (l >> 4) * 4;
      if (OUT == 0) {
        float bv = bias[col];
#pragma unroll
        for (int j = 0; j < 4; ++j)
          ((float*)C)[(rbase + j) * (size_t)ldc + col] = acc[m][n][j] * alpha + bv;
      } else if (OUT == 1) {
#pragma unroll
        for (int j = 0; j < 4; ++j)
          ((u16*)C)[(rbase + j) * (size_t)ldc + col] = f2bf(acc[m][n][j] * alpha);
      } else {
        u16x4 p;
#pragma unroll
        for (int j = 0; j < 4; ++j) p[j] = f2bf(acc[m][n][j] * alpha);
        *(u16x4*)&((u16*)C)[col * (size_t)ldc + rbase] = p;
      }
    }
  }
}

// ---------------- shared GEMM macros (256^2, 8 waves, BK=64) ----------------

template <int VM>
__device__ __forceinline__ void waitvm() {
  if constexpr (VM == 4) asm volatile("s_waitcnt vmcnt(4)" ::: "memory");
  else asm volatile("s_waitcnt vmcnt(0)" ::: "memory");
}
#define FENCE asm volatile("" ::: "memory")
#define BARRIER do { FENCE; __builtin_amdgcn_s_barrier(); FENCE; } while (0)

#define SGA(UNIT, KT, BUF)                                                          \
  __builtin_amdgcn_global_load_lds(                                                 \
      (gu32*)(Agp + (size_t)((UNIT) * 64) * ldaB + (size_t)(KT) * 128),             \
      (lu32*)(smem + (BUF) * 16384 + (UNIT) * 4096 + tid * 8), 16, 0, 0)

#define SGB(UNIT, KT, BUF)                                                          \
  do {                                                                              \
    int _rp = (UNIT) * 64 + rr;                                                     \
    size_t _row = (size_t)(bn0 + ((_rp >> 5) & 3) * 64 + (_rp >> 7) * 32 + (_rp & 31)); \
    __builtin_amdgcn_global_load_lds(                                               \
        (gu32*)(Bgp + _row * ldbB + (size_t)(KT) * 128),                            \
        (lu32*)(smem + 32768 + (BUF) * 16384 + (UNIT) * 4096 + tid * 8), 16, 0, 0); \
  } while (0)

#define RDA4(DST, BO, MQ, KO)                                                       \
  _Pragma("unroll") for (int fr = 0; fr < 4; ++fr)                                  \
    DST[fr] = *(const short8*)(smemc + (BO) + aRd + (MQ) * 8192 + fr * 2048 + (KO));

#define RDB2(NQ_, KK, BO, KO)                                                       \
  _Pragma("unroll") for (int fc = 0; fc < 2; ++fc)                                  \
    bf[NQ_][KK][fc] = *(const short8*)(smemc + 65536 + (BO) + bRd + (NQ_) * 16384 + fc * 2048 + (KO));

#define MM8(AF, MQ, NQ_, KK)                                                        \
  do {                                                                              \
    __builtin_amdgcn_s_setprio(1);                                                  \
    _Pragma("unroll") for (int fr = 0; fr < 4; ++fr)                                \
    _Pragma("unroll") for (int fc = 0; fc < 2; ++fc)                                \
      acc[(MQ) * 4 + fr][(NQ_) * 2 + fc] = __builtin_amdgcn_mfma_f32_16x16x32_bf16( \
          AF[fr], bf[NQ_][KK][fc], acc[(MQ) * 4 + fr][(NQ_) * 2 + fc], 0, 0, 0);    \
    __builtin_amdgcn_s_setprio(0);                                                  \
  } while (0)

#define GEMM_SETUP                                                                  \
  __shared__ __align__(16) u16 smem[65536];                                         \
  const char* smemc = (const char*)smem;                                            \
  const int tid = threadIdx.x;                                                      \
  const int l = tid & 63;                                                           \
  const int wid = tid >> 6;                                                         \
  const int wm = wid >> 2, wn = wid & 3;                                            \
  const int lane_r = l & 15;                                                        \
  const int kq = l >> 4;                                                            \
  const int rr = tid >> 3;                                                          \
  const int bid = blockIdx.x;                                                       \
  const int xcd = bid & 7;                                                          \
  const int c = bid >> 3;                                                           \
  const int tm = xcd * tmb + (c % tmb);                                             \
  const int tn = c / tmb;                                                           \
  const int am0 = tm * 256, bn0 = tn * 256;                                         \
  const size_t kglob = kspanB * blockIdx.y;                                         \
  const int kx = (lane_r & 7) << 4;                                                 \
  const int koff0 = (kq << 4) ^ kx;                                                 \
  const int koff1 = (64 | (kq << 4)) ^ kx;                                          \
  const int aRd = (wm * 128 + lane_r) * 128;                                        \
  const int bRd = (wn * 32 + lane_r) * 128;                                         \
  const int scol = ((tid & 7) ^ ((tid >> 3) & 7)) << 4;                             \
  const char* Agp = (const char*)A + (size_t)(am0 + rr) * ldaB + kglob + scol;      \
  const char* Bgp = (const char*)Bt + kglob + scol;                                 \
  f32x4 acc[8][4];                                                                  \
  _Pragma("unroll") for (int i = 0; i < 8; ++i)                                     \
  _Pragma("unroll") for (int j = 0; j < 4; ++j) acc[i][j] = (f32x4){0.f, 0.f, 0.f, 0.f};

// ---------------- R5-schedule 256^2 kernel (all GEMMs) ----------------
// OUT: 0 = bf16 store; 1 = bf16 split-K partial at C + cstride*blockIdx.y;
//      2 = fused qkv projection (band by am0>>13: Wq/Wk/Wv -> qh/kh/vhT^T);
//      3 = f32 store + bias (out-projection);
//      4 = QK^T fused bias+exp epilogue (no-max softmax; pre-scaled centers)

template <int OUT>
__global__ __launch_bounds__(512, 2) void gemm256_kernel(
    const u16* __restrict__ A, const u16* __restrict__ Bt, void* __restrict__ C,
    const float* __restrict__ bias, const float2* __restrict__ cqp,
    const float2* __restrict__ crp, const float* __restrict__ bwp,
    float* __restrict__ psum, int NT, int nTn, int tmb,
    size_t ldaB, size_t ldbB, int ldc, size_t kspanB, size_t cstride, float alpha) {
  GEMM_SETUP;

  int band = 0;
  const u16* Bt2 = Bt;
  if (OUT == 2) { band = am0 >> 13; Bt2 = Bt + ((size_t)band << 20); }
  const char* Bgp2 = (const char*)Bt2 + kglob + scol;
  #define Bgp Bgp2

  short8 afP[4], afQ[4], bf[2][2][2];

  // prologue: tile0 -> buf0 (early-consumed units first)
  SGA(0, 0, 0); SGA(2, 0, 0); SGB(0, 0, 0); SGB(1, 0, 0);
  SGB(2, 0, 0); SGB(3, 0, 0); SGA(1, 0, 0); SGA(3, 0, 0);
  waitvm<0>();
  BARRIER;
  RDA4(afP, 0, 0, koff0);
  RDB2(0, 0, 0, koff0);

  for (int t = 0; t < NT; ++t) {
    const int bo = (t & 1) * 32768;
    const int nbo = bo ^ 32768;
    const int nb = (t & 1) ^ 1;
    const bool more = (t + 1 < NT);
    if (more) { SGA(0, t + 1, nb); SGA(2, t + 1, nb); }
    RDB2(1, 0, bo, koff0);
    MM8(afP, 0, 0, 0);
    if (more) { SGB(0, t + 1, nb); SGB(1, t + 1, nb); }
    RDA4(afQ, bo, 1, koff0);
    MM8(afP, 0, 1, 0);
    if (more) { SGB(2, t + 1, nb); SGB(3, t + 1, nb); }
    RDB2(0, 1, bo, koff1);
    MM8(afQ, 1, 1, 0);
    if (more) { SGA(1, t + 1, nb); SGA(3, t + 1, nb); }
    RDA4(afP, bo, 1, koff1);
    MM8(afQ, 1, 0, 0);
    RDB2(1, 1, bo, koff1);
    MM8(afP, 1, 0, 1);
    RDA4(afQ, bo, 0, koff1);
    MM8(afP, 1, 1, 1);
    MM8(afQ, 0, 1, 1);
    waitvm<4>();
    BARRIER;
    if (more) { RDA4(afP, nbo, 0, koff0); RDB2(0, 0, nbo, koff0); }
    MM8(afQ, 0, 0, 1);
    waitvm<0>();
    BARRIER;
  }
  #undef Bgp

  // ---------------- epilogue (16x16x32 C layout: col = lane&15, row = kq*4+j) ----
  if (OUT == 4) {
    const float sc = bwp[0] * 1.44269504f;
    const float eps2 = sc * sc * 1e-8f;
    float* psld = (float*)smem;
    float2 crv[4];
#pragma unroll
    for (int fc2 = 0; fc2 < 4; ++fc2) crv[fc2] = crp[bn0 + wn * 64 + fc2 * 16 + lane_r];
#pragma unroll
    for (int fp = 0; fp < 8; ++fp) {
      float rs[4] = {0.f, 0.f, 0.f, 0.f};
      int rbase = am0 + wm * 128 + fp * 16 + kq * 4;
#pragma unroll
      for (int j = 0; j < 4; ++j) {
        float2 cqv = cqp[rbase + j];
#pragma unroll
        for (int fc2 = 0; fc2 < 4; ++fc2) {
          float dx = cqv.x - crv[fc2].x, dy = cqv.y - crv[fc2].y;
          float d2v = fmaf(dx, dx, fmaf(dy, dy, eps2));
          float D;
          asm("v_sqrt_f32 %0, %1" : "=v"(D) : "v"(d2v));
          float l2 = fmaf(acc[fp][fc2][j], 1.44269504f, -D);
          float pv;
          asm("v_exp_f32 %0, %1" : "=v"(pv) : "v"(l2));
          rs[j] += pv;
          int col = bn0 + wn * 64 + fc2 * 16 + lane_r;
          ((u16*)C)[(size_t)(rbase + j) * ldc + col] = f2bf(pv);
        }
      }
#pragma unroll
      for (int j = 0; j < 4; ++j) {
        float s = rs[j];
        s += __shfl_xor(s, 1); s += __shfl_xor(s, 2);
        s += __shfl_xor(s, 4); s += __shfl_xor(s, 8);
        if (lane_r == 0)
          psld[(wm * 128 + fp * 16 + kq * 4 + j) * 4 + wn] = s;
      }
    }
    __syncthreads();
    if (tid < 256) {
      float s = psld[tid * 4] + psld[tid * 4 + 1] + psld[tid * 4 + 2] + psld[tid * 4 + 3];
      psum[(size_t)tn * NQ + am0 + tid] = s;
    }
    return;
  }
#pragma unroll
  for (int fp = 0; fp < 8; ++fp) {
#pragma unroll
    for (int fc2 = 0; fc2 < 4; ++fc2) {
      int row = am0 + wm * 128 + fp * 16 + kq * 4;
      int col = bn0 + wn * 64 + fc2 * 16 + lane_r;
      if (OUT == 0) {
#pragma unroll
        for (int j = 0; j < 4; ++j)
          ((u16*)C)[(size_t)(row + j) * ldc + col] = f2bf(acc[fp][fc2][j] * alpha);
      } else if (OUT == 1) {
        u16* Cp = (u16*)C + cstride * blockIdx.y;
#pragma unroll
        for (int j = 0; j < 4; ++j)
          Cp[(size_t)(row + j) * ldc + col] = f2bf(acc[fp][fc2][j]);
      } else if (OUT == 3) {
        float* Cf = (float*)C;
        float bv = bias[col];
#pragma unroll
        for (int j = 0; j < 4; ++j)
          Cf[(size_t)(row + j) * ldc + col] = acc[fp][fc2][j] * alpha + bv;
      } else {
        int arow = row & 8191;
        if (band < 2) {
          u16* D = (u16*)C + ((size_t)band << 23);  // qh / kh
          float a2 = (band == 0) ? 0.03125f : 1.f;
#pragma unroll
          for (int j = 0; j < 4; ++j)
            D[(size_t)(arow + j) * DIM + col] = f2bf(acc[fp][fc2][j] * a2);
        } else {
          u16* D = (u16*)C + ((size_t)2 << 23);     // vhT (transposed)
          u16x4 pk;
#pragma unroll
          for (int j = 0; j < 4; ++j) pk[j] = f2bf(acc[fp][fc2][j]);
          *(u16x4*)&D[(size_t)col * NK + arow] = pk;
        }
      }
    }
  }
}

// ---------------- row-sum inverse: inv[r] = 1 / sum_t psum[t][r] ----------------

__global__ void rowinv_kernel(const float* __restrict__ psum, float* __restrict__ inv) {
  int r = blockIdx.x * 256 + threadIdx.x;
  float s = 0.f;
#pragma unroll
  for (int t = 0; t < 32; ++t) s += psum[(size_t)t * NQ + r];
  inv[r] = 1.f / s;
}

// ---------------- split-K=2 combine with row normalization ----------------

__global__ void combine2_kernel(const u16x8* __restrict__ p, const float* __restrict__ inv,
                                u16x8* __restrict__ out) {
  const size_t st = (size_t)NQ * DIM / 8;
  size_t i = (size_t)blockIdx.x * 256 + threadIdx.x;
  u16x8 a = p[i], b = p[i + st];
  float iv = inv[i >> 7];
  u16x8 o;
#pragma unroll
  for (int j = 0; j < 8; ++j)
    o[j] = f2bf((bf2f(a[j]) + bf2f(b[j])) * iv);
  out[i] = o;
}

// ---------------- fused bias + row softmax, bf16 in place (fallback path) --------

__global__ __launch_bounds__(256) void softmax_bias_bf16_kernel(
    u16* __restrict__ S, const float2* __restrict__ cq, const float2* __restrict__ cr,
    const float* __restrict__ bwp, int qr0) {
  __shared__ float red[256];
  const int t = threadIdx.x;
  u16* row = S + (size_t)blockIdx.x * NK;
  const float2 cqv = cq[qr0 + blockIdx.x];
  const float bw = bwp[0];

  float l[32];
  float mx = -1e30f;
#pragma unroll
  for (int i = 0; i < 4; ++i) {
    int base = (i * 256 + t) * 8;
    u16x8 u = *(const u16x8*)&row[base];
#pragma unroll
    for (int j = 0; j < 8; ++j) {
      float x = bf2f(u[j]);
      float2 c = cr[base + j];
      float dx = cqv.x - c.x, dy = cqv.y - c.y;
      float lv = x - bw * sqrtf(dx * dx + dy * dy + 1e-8f);
      l[i * 8 + j] = lv;
      mx = fmaxf(mx, lv);
    }
  }
  red[t] = mx; __syncthreads();
  for (int s = 128; s > 0; s >>= 1) { if (t < s) red[t] = fmaxf(red[t], red[t + s]); __syncthreads(); }
  mx = red[0]; __syncthreads();

  float sum = 0.f;
#pragma unroll
  for (int i = 0; i < 32; ++i) { float e = __expf(l[i] - mx); l[i] = e; sum += e; }
  red[t] = sum; __syncthreads();
  for (int s = 128; s > 0; s >>= 1) { if (t < s) red[t] += red[t + s]; __syncthreads(); }
  float inv = 1.f / red[0];

#pragma unroll
  for (int i = 0; i < 4; ++i) {
    int base = (i * 256 + t) * 8;
    u16x8 o;
#pragma unroll
    for (int j = 0; j < 8; ++j) o[j] = f2bf(l[i * 8 + j] * inv);
    *(u16x8*)&row[base] = o;
  }
}

// ---------------- host ----------------

extern "C" void kernel_launch(void* const* d_in, const int* in_sizes, int n_in,
                              void* d_out, int out_size, void* d_ws, size_t ws_size,
                              hipStream_t stream) {
  const float* q  = (const float*)d_in[0];
  const float* k  = (const float*)d_in[1];
  const float* v  = (const float*)d_in[2];
  const float* rb = (const float*)d_in[3];
  const float* qb = (const float*)d_in[4];
  const float* Wq = (const float*)d_in[5];
  const float* Wk = (const float*)d_in[6];
  const float* Wv = (const float*)d_in[7];
  const float* Wp = (const float*)d_in[8];
  const float* bp = (const float*)d_in[9];
  const float* W1 = (const float*)d_in[10];
  const float* b1 = (const float*)d_in[11];
  const float* W2 = (const float*)d_in[12];
  const float* b2 = (const float*)d_in[13];
  float* out = (float*)d_out;

  // qbf|kbf dead after proj -> hold the two 16 MB bf16 split-K partials of PV.
  char* p = (char*)d_ws;
  const size_t PROJB = (size_t)NQ * DIM * sizeof(u16);  // 16 MB
  u16* qbf = (u16*)p;            p += PROJB;
  u16* kbf = (u16*)p;            p += PROJB;
  u16* vbf = (u16*)p;            p += PROJB;
  u16* qh  = (u16*)p;            p += PROJB;
  u16* kh  = (u16*)p;            p += PROJB;
  u16* vhT = (u16*)p;            p += PROJB;
  u16* WqT = (u16*)p;            p += (size_t)DIM * DIM * 2;
  u16* WkT = (u16*)p;            p += (size_t)DIM * DIM * 2;
  u16* WvT = (u16*)p;            p += (size_t)DIM * DIM * 2;
  u16* WpT = (u16*)p;            p += (size_t)DIM * DIM * 2;
  float* cq  = (float*)p;        p += 2 * NQ * 4;
  float* cr  = (float*)p;        p += 2 * NK * 4;
  float* cqs = (float*)p;        p += 2 * NQ * 4;
  float* crs = (float*)p;        p += 2 * NK * 4;
  float* ps  = (float*)p;        p += 32 * DIM * 4;   // fallback var partials
  float* pq  = (float*)p;        p += 32 * DIM * 4;
  float* gfv = (float*)p;        p += DIM * 4;
  float* h1p = (float*)p;        p += 8 * 2048 * 4;
  float* bw  = (float*)p;        p += 64;
  float* psum = (float*)p;       p += (size_t)32 * NQ * 4;
  float* rinv = (float*)p;       p += (size_t)NQ * 4;
  size_t fixed_b = (size_t)(p - (char*)d_ws);

  int SR = 256;
  for (int cand = 8192; cand >= 256; cand >>= 1) {
    if (fixed_b + (size_t)cand * (NK + DIM) * 2 <= ws_size) { SR = cand; break; }
  }
  u16* Sbuf = (u16*)p;
  u16* Obuf = Sbuf + (size_t)SR * NK;

  const int N4 = NQ * DIM / 4;

  if (SR == 8192) {
    // var partials fused into f2bf3's k-branch; partials live in the (not yet
    // written) Sbuf region: psB[1024][1024] + pqB[1024][1024] = 8 MB.
    float* psB = (float*)Sbuf;
    float* pqB = psB + (size_t)1024 * DIM;
    f2bf3_kernel<<<dim3(1024, 3), 256, 0, stream>>>(
        (const float4*)q, (const float4*)k, (const float4*)v,
        (u16x4*)qbf, (u16x4*)kbf, (u16x4*)vbf, N4, psB, pqB);
    var_reduce_kernel<<<32, 256, 0, stream>>>(psB, pqB, gfv);
  } else {
    f2bf3_kernel<<<dim3(1024, 3), 256, 0, stream>>>(
        (const float4*)q, (const float4*)k, (const float4*)v,
        (u16x4*)qbf, (u16x4*)kbf, (u16x4*)vbf, N4, nullptr, nullptr);
    var_partial_kernel<<<dim3(4, 32), 256, 0, stream>>>(k, ps, pq);
    gfv_kernel<<<4, 256, 0, stream>>>(ps, pq, gfv, 32);
  }
  h1_partial_kernel<<<dim3(8, 8), 256, 0, stream>>>(gfv, W1, h1p);
  bw_kernel<<<1, 256, 0, stream>>>(h1p, b1, W2, b2, bw);
  centers_kernel<<<32, 256, 0, stream>>>((const float4*)qb, (const float4*)rb, bw,
                                         (float2*)cq, (float2*)cr,
                                         (float2*)cqs, (float2*)crs);
  wtrans4_kernel<<<dim3(16, 16, 4), 256, 0, stream>>>(Wq, Wk, Wv, Wp, WqT, WkT, WvT, WpT);

  // fused q/k/v projections (R5 schedule)
  gemm256_kernel<2><<<dim3(384, 1), 512, 0, stream>>>(
      qbf, WqT, qh, nullptr, nullptr, nullptr, nullptr, nullptr,
      16, 4, 12, 2048, 2048, DIM, 0, 0, 1.f);

  if (SR == 8192) {
    // S = exp(qh @ kh^T - bw*dist) fused (scaled centers); row sums -> psum
    // (overwrites the psB/pqB scratch — var chain already consumed it)
    gemm256_kernel<4><<<dim3(1024, 1), 512, 0, stream>>>(
        qh, kh, Sbuf, nullptr, (const float2*)cqs, (const float2*)crs, bw, psum,
        16, 32, 4, 2048, 2048, NK, 0, 0, 1.f);
    rowinv_kernel<<<32, 256, 0, stream>>>(psum, rinv);
    // O' = P' @ vh, split-K=2 (256 blocks = 1/CU, NT=64), bf16 partials in qbf|kbf
    gemm256_kernel<1><<<dim3(128, 2), 512, 0, stream>>>(
        Sbuf, vhT, qbf, nullptr, nullptr, nullptr, nullptr, nullptr,
        64, 4, 4, 16384, 16384, DIM, 8192, (size_t)NQ * DIM, 1.f);
    combine2_kernel<<<4096, 256, 0, stream>>>((const u16x8*)qbf, rinv, (u16x8*)Obuf);
    // out = O @ Wp + bp
    gemm256_kernel<3><<<dim3(128, 1), 512, 0, stream>>>(
        Obuf, WpT, out, bp, nullptr, nullptr, nullptr, nullptr,
        16, 4, 4, 2048, 2048, DIM, 0, 0, 1.f);
  } else {
    for (int s0 = 0; s0 < NQ; s0 += SR) {
      bgemm_kernel<1><<<dim3(NK / TN, SR / TM), 256, 0, stream>>>(
          qh + (size_t)s0 * DIM, kh, Sbuf, nullptr, SR, NK, DIM, NK, 1.f);
      softmax_bias_bf16_kernel<<<SR, 256, 0, stream>>>(
          Sbuf, (const float2*)cq, (const float2*)cr, bw, s0);
      bgemm_kernel<1><<<dim3(DIM / TN, SR / TM), 256, 0, stream>>>(
          Sbuf, vhT, Obuf, nullptr, SR, DIM, NK, DIM, 1.f);
      bgemm_kernel<0><<<dim3(DIM / TN, SR / TM), 256, 0, stream>>>(
          Obuf, WpT, out + (size_t)s0 * DIM, bp, SR, DIM, DIM, DIM, 1.f);
    }
  }
}

// Round 14
// 401.232 us; speedup vs baseline: 1.6142x; 1.0171x over previous
//
#include <hip/hip_runtime.h>
#include <math.h>

#define DIM 1024
#define NQ 8192
#define NK 8192

typedef unsigned short u16;
typedef __attribute__((ext_vector_type(8))) short short8;
typedef __attribute__((ext_vector_type(8))) u16 u16x8;
typedef __attribute__((ext_vector_type(4))) u16 u16x4;
typedef __attribute__((ext_vector_type(4))) float f32x4;
typedef __attribute__((address_space(1))) const unsigned int gu32;
typedef __attribute__((address_space(3))) unsigned int lu32;

__device__ inline u16 f2bf(float f) {
  unsigned u = __builtin_bit_cast(unsigned, f);
  u += 0x7fff + ((u >> 16) & 1);
  return (u16)(u >> 16);
}
__device__ inline float bf2f(u16 h) {
  unsigned u = ((unsigned)h) << 16;
  return __builtin_bit_cast(float, u);
}

// ---------------- small kernels: var -> MLP -> bias_weight ----------------

// fallback-only separate var pass
__global__ void var_partial_kernel(const float* __restrict__ k,
                                   float* __restrict__ ps, float* __restrict__ pq) {
  int col = blockIdx.x * 256 + threadIdx.x;
  int r0  = blockIdx.y * 256;
  float s = 0.f, q = 0.f;
  for (int r = 0; r < 256; ++r) {
    float x = k[(size_t)(r0 + r) * DIM + col];
    s += x; q += x * x;
  }
  ps[blockIdx.y * DIM + col] = s;
  pq[blockIdx.y * DIM + col] = q;
}

__global__ void gfv_kernel(const float* __restrict__ ps, const float* __restrict__ pq,
                           float* __restrict__ gfv, int np) {
  int col = blockIdx.x * 256 + threadIdx.x;
  float s = 0.f, q = 0.f;
  for (int c = 0; c < np; ++c) { s += ps[(size_t)c * DIM + col]; q += pq[(size_t)c * DIM + col]; }
  const float n = 8192.f;
  gfv[col] = (q - s * s / n) / (n - 1.f);  // unbiased var (ddof=1)
}

// hierarchical reduction of 1024x1024 partials (fused-var path).
__global__ __launch_bounds__(256) void var_reduce_kernel(
    const float* __restrict__ psB, const float* __restrict__ pqB,
    float* __restrict__ gfv) {
  __shared__ float sred[8][33], qred[8][33];
  const int t = threadIdx.x;
  const int cl = t & 31;
  const int rg = t >> 5;
  const int col = blockIdx.x * 32 + cl;
  float s = 0.f, q = 0.f;
  for (int r = rg * 128; r < rg * 128 + 128; ++r) {
    s += psB[(size_t)r * DIM + col];
    q += pqB[(size_t)r * DIM + col];
  }
  sred[rg][cl] = s; qred[rg][cl] = q;
  __syncthreads();
  if (rg == 0) {
#pragma unroll
    for (int g = 1; g < 8; ++g) { s += sred[g][cl]; q += qred[g][cl]; }
    const float n = 8192.f;
    gfv[col] = (q - s * s / n) / (n - 1.f);
  }
}

__global__ void h1_partial_kernel(const float* __restrict__ gfv, const float* __restrict__ W1,
                                  float* __restrict__ h1p) {
  int j  = blockIdx.x * 256 + threadIdx.x;
  int d0 = blockIdx.y * 128;
  float acc = 0.f;
  for (int d = 0; d < 128; ++d)
    acc += gfv[d0 + d] * W1[(size_t)(d0 + d) * 2048 + j];
  h1p[blockIdx.y * 2048 + j] = acc;
}

__global__ void bw_kernel(const float* __restrict__ h1p, const float* __restrict__ b1,
                          const float* __restrict__ W2, const float* __restrict__ b2,
                          float* __restrict__ bw) {
  __shared__ float red[256];
  int t = threadIdx.x;
  float acc = 0.f;
  for (int i = 0; i < 8; ++i) {
    int j = i * 256 + t;
    float h = b1[j];
    for (int c = 0; c < 8; ++c) h += h1p[c * 2048 + j];
    h = fmaxf(h, 0.f);
    acc += h * W2[j];
  }
  red[t] = acc; __syncthreads();
  for (int s = 128; s > 0; s >>= 1) { if (t < s) red[t] += red[t + s]; __syncthreads(); }
  if (t == 0) bw[0] = 1.f / (1.f + __expf(-(red[0] + b2[0])));
}

// centers: unscaled (cq,cr for fallback) + scaled by bw*log2e (cqs,crs for fused path)
__global__ void centers_kernel(const float4* __restrict__ qb, const float4* __restrict__ rb,
                               const float* __restrict__ bwp,
                               float2* __restrict__ cq, float2* __restrict__ cr,
                               float2* __restrict__ cqs, float2* __restrict__ crs) {
  int i = blockIdx.x * 256 + threadIdx.x;
  const float sc = bwp[0] * 1.44269504f;
  float4 a = qb[i];
  float2 c1 = make_float2(0.5f * (a.x + a.z), 0.5f * (a.y + a.w));
  cq[i] = c1;
  cqs[i] = make_float2(c1.x * sc, c1.y * sc);
  float4 b = rb[i];
  float2 c2 = make_float2(0.5f * (b.x + b.z), 0.5f * (b.y + b.w));
  cr[i] = c2;
  crs[i] = make_float2(c2.x * sc, c2.y * sc);
}

// ---------------- conversion kernels (fused launches) ----------------

__global__ void f2bf3_kernel(const float4* __restrict__ a, const float4* __restrict__ b,
                             const float4* __restrict__ c, u16x4* __restrict__ oa,
                             u16x4* __restrict__ ob, u16x4* __restrict__ oc, int n4,
                             float* __restrict__ psB, float* __restrict__ pqB) {
  const float4* in = (blockIdx.y == 0) ? a : (blockIdx.y == 1) ? b : c;
  u16x4* out = (blockIdx.y == 0) ? oa : (blockIdx.y == 1) ? ob : oc;
  if (blockIdx.y == 1 && psB) {
    const int t = threadIdx.x, blk = blockIdx.x;
    float4 s = make_float4(0.f, 0.f, 0.f, 0.f);
    float4 q = make_float4(0.f, 0.f, 0.f, 0.f);
#pragma unroll
    for (int j = 0; j < 8; ++j) {
      int i = blk * 256 + t + j * 262144;
      float4 v = in[i];
      s.x += v.x; s.y += v.y; s.z += v.z; s.w += v.w;
      q.x += v.x * v.x; q.y += v.y * v.y; q.z += v.z * v.z; q.w += v.w * v.w;
      u16x4 o;
      o[0] = f2bf(v.x); o[1] = f2bf(v.y); o[2] = f2bf(v.z); o[3] = f2bf(v.w);
      out[i] = o;
    }
    ((float4*)(psB + (size_t)blk * DIM))[t] = s;
    ((float4*)(pqB + (size_t)blk * DIM))[t] = q;
    return;
  }
  for (int i = blockIdx.x * 256 + threadIdx.x; i < n4; i += gridDim.x * 256) {
    float4 v = in[i];
    u16x4 o;
    o[0] = f2bf(v.x); o[1] = f2bf(v.y); o[2] = f2bf(v.z); o[3] = f2bf(v.w);
    out[i] = o;
  }
}

// transpose-convert 4x 1024x1024 f32 W -> bf16 WT[n][k] = W[k][n]
__global__ __launch_bounds__(256) void wtrans4_kernel(
    const float* __restrict__ W0, const float* __restrict__ W1,
    const float* __restrict__ W2, const float* __restrict__ W3,
    u16* __restrict__ T0, u16* __restrict__ T1, u16* __restrict__ T2, u16* __restrict__ T3) {
  const float* W = (blockIdx.z == 0) ? W0 : (blockIdx.z == 1) ? W1 : (blockIdx.z == 2) ? W2 : W3;
  u16* WT = (blockIdx.z == 0) ? T0 : (blockIdx.z == 1) ? T1 : (blockIdx.z == 2) ? T2 : T3;
  __shared__ float tile[64][65];
  const int t = threadIdx.x;
  const int kb = blockIdx.x * 64, nb = blockIdx.y * 64;
#pragma unroll
  for (int i = 0; i < 16; ++i) {
    int r = i * 4 + (t >> 6), c = t & 63;
    tile[c][r] = W[(size_t)(kb + r) * 1024 + nb + c];
  }
  __syncthreads();
#pragma unroll
  for (int i = 0; i < 16; ++i) {
    int n = i * 4 + (t >> 6), kk = t & 63;
    WT[(size_t)(nb + n) * 1024 + kb + kk] = f2bf(tile[n][kk]);
  }
}

// ---------------- 128x128 bf16 MFMA GEMM (fallback only) ----------------

#define TM 128
#define TN 128
#define TK 32

template <int OUT>
__global__ __launch_bounds__(256) void bgemm_kernel(
    const u16* __restrict__ A, const u16* __restrict__ Bt, void* __restrict__ C,
    const float* __restrict__ bias, int M, int N, int K, int ldc, float alpha) {
  __shared__ __align__(16) u16 As[TM * TK];
  __shared__ __align__(16) u16 Bs[TN * TK];

  const int t = threadIdx.x;
  const int l = t & 63;
  const int w = t >> 6;
  const int wm = w >> 1, wn = w & 1;
  const size_t row0 = (size_t)blockIdx.y * TM;
  const size_t col0 = (size_t)blockIdx.x * TN;

  f32x4 acc[4][4];
#pragma unroll
  for (int m = 0; m < 4; ++m)
#pragma unroll
    for (int n = 0; n < 4; ++n) acc[m][n] = (f32x4){0.f, 0.f, 0.f, 0.f};

  const int lane_r = l & 15;
  const int kgrp = (l >> 4) * 8;

  for (int k0 = 0; k0 < K; k0 += TK) {
#pragma unroll
    for (int j = 0; j < 2; ++j) {
      int idx = j * 256 + t;
      int r = idx >> 2, c8 = (idx & 3) << 3;
      __builtin_amdgcn_global_load_lds((gu32*)(A + (row0 + r) * K + k0 + c8),
                                       (lu32*)(As + idx * 8), 16, 0, 0);
      __builtin_amdgcn_global_load_lds((gu32*)(Bt + (col0 + r) * K + k0 + c8),
                                       (lu32*)(Bs + idx * 8), 16, 0, 0);
    }
    __syncthreads();

    short8 a[4], b[4];
#pragma unroll
    for (int m = 0; m < 4; ++m)
      a[m] = *(const short8*)&As[(wm * 64 + m * 16 + lane_r) * TK + kgrp];
#pragma unroll
    for (int n = 0; n < 4; ++n)
      b[n] = *(const short8*)&Bs[(wn * 64 + n * 16 + lane_r) * TK + kgrp];
#pragma unroll
    for (int m = 0; m < 4; ++m)
#pragma unroll
      for (int n = 0; n < 4; ++n)
        acc[m][n] = __builtin_amdgcn_mfma_f32_16x16x32_bf16(a[m], b[n], acc[m][n], 0, 0, 0);
    __syncthreads();
  }

#pragma unroll
  for (int m = 0; m < 4; ++m) {
#pragma unroll
    for (int n = 0; n < 4; ++n) {
      size_t col = col0 + wn * 64 + n * 16 + lane_r;
      size_t rbase = row0 + wm * 64 + m * 16 + (l >> 4) * 4;
      if (OUT == 0) {
        float bv = bias[col];
#pragma unroll
        for (int j = 0; j < 4; ++j)
          ((float*)C)[(rbase + j) * (size_t)ldc + col] = acc[m][n][j] * alpha + bv;
      } else if (OUT == 1) {
#pragma unroll
        for (int j = 0; j < 4; ++j)
          ((u16*)C)[(rbase + j) * (size_t)ldc + col] = f2bf(acc[m][n][j] * alpha);
      } else {
        u16x4 p;
#pragma unroll
        for (int j = 0; j < 4; ++j) p[j] = f2bf(acc[m][n][j] * alpha);
        *(u16x4*)&((u16*)C)[col * (size_t)ldc + rbase] = p;
      }
    }
  }
}

// ---------------- shared GEMM macros (256^2, 8 waves, BK=64) ----------------

template <int VM>
__device__ __forceinline__ void waitvm() {
  if constexpr (VM == 4) asm volatile("s_waitcnt vmcnt(4)" ::: "memory");
  else asm volatile("s_waitcnt vmcnt(0)" ::: "memory");
}
#define FENCE asm volatile("" ::: "memory")
#define BARRIER do { FENCE; __builtin_amdgcn_s_barrier(); FENCE; } while (0)

#define SGA(UNIT, KT, BUF)                                                          \
  __builtin_amdgcn_global_load_lds(                                                 \
      (gu32*)(Agp + (size_t)((UNIT) * 64) * ldaB + (size_t)(KT) * 128),             \
      (lu32*)(smem + (BUF) * 16384 + (UNIT) * 4096 + tid * 8), 16, 0, 0)

#define SGB(UNIT, KT, BUF)                                                          \
  do {                                                                              \
    int _rp = (UNIT) * 64 + rr;                                                     \
    size_t _row = (size_t)(bn0 + ((_rp >> 5) & 3) * 64 + (_rp >> 7) * 32 + (_rp & 31)); \
    __builtin_amdgcn_global_load_lds(                                               \
        (gu32*)(Bgp + _row * ldbB + (size_t)(KT) * 128),                            \
        (lu32*)(smem + 32768 + (BUF) * 16384 + (UNIT) * 4096 + tid * 8), 16, 0, 0); \
  } while (0)

#define RDA4(DST, BO, MQ, KO)                                                       \
  _Pragma("unroll") for (int fr = 0; fr < 4; ++fr)                                  \
    DST[fr] = *(const short8*)(smemc + (BO) + aRd + (MQ) * 8192 + fr * 2048 + (KO));

#define RDB2(NQ_, KK, BO, KO)                                                       \
  _Pragma("unroll") for (int fc = 0; fc < 2; ++fc)                                  \
    bf[NQ_][KK][fc] = *(const short8*)(smemc + 65536 + (BO) + bRd + (NQ_) * 16384 + fc * 2048 + (KO));

#define MM8(AF, MQ, NQ_, KK)                                                        \
  do {                                                                              \
    __builtin_amdgcn_s_setprio(1);                                                  \
    _Pragma("unroll") for (int fr = 0; fr < 4; ++fr)                                \
    _Pragma("unroll") for (int fc = 0; fc < 2; ++fc)                                \
      acc[(MQ) * 4 + fr][(NQ_) * 2 + fc] = __builtin_amdgcn_mfma_f32_16x16x32_bf16( \
          AF[fr], bf[NQ_][KK][fc], acc[(MQ) * 4 + fr][(NQ_) * 2 + fc], 0, 0, 0);    \
    __builtin_amdgcn_s_setprio(0);                                                  \
  } while (0)

#define GEMM_SETUP                                                                  \
  __shared__ __align__(16) u16 smem[65536];                                         \
  const char* smemc = (const char*)smem;                                            \
  const int tid = threadIdx.x;                                                      \
  const int l = tid & 63;                                                           \
  const int wid = tid >> 6;                                                         \
  const int wm = wid >> 2, wn = wid & 3;                                            \
  const int lane_r = l & 15;                                                        \
  const int kq = l >> 4;                                                            \
  const int rr = tid >> 3;                                                          \
  const int bid = blockIdx.x;                                                       \
  const int xcd = bid & 7;                                                          \
  const int c = bid >> 3;                                                           \
  const int tm = xcd * tmb + (c % tmb);                                             \
  const int tn = c / tmb;                                                           \
  const int am0 = tm * 256, bn0 = tn * 256;                                         \
  const size_t kglob = kspanB * blockIdx.y;                                         \
  const int kx = (lane_r & 7) << 4;                                                 \
  const int koff0 = (kq << 4) ^ kx;                                                 \
  const int koff1 = (64 | (kq << 4)) ^ kx;                                          \
  const int aRd = (wm * 128 + lane_r) * 128;                                        \
  const int bRd = (wn * 32 + lane_r) * 128;                                         \
  const int scol = ((tid & 7) ^ ((tid >> 3) & 7)) << 4;                             \
  const char* Agp = (const char*)A + (size_t)(am0 + rr) * ldaB + kglob + scol;      \
  const char* Bgp = (const char*)Bt + kglob + scol;                                 \
  f32x4 acc[8][4];                                                                  \
  _Pragma("unroll") for (int i = 0; i < 8; ++i)                                     \
  _Pragma("unroll") for (int j = 0; j < 4; ++j) acc[i][j] = (f32x4){0.f, 0.f, 0.f, 0.f};

// ---------------- R5-schedule 256^2 kernel (all GEMMs) ----------------
// OUT: 0 = bf16 store; 1 = bf16 split-K partial at C + cstride*blockIdx.y;
//      2 = fused qkv projection (band by am0>>13: Wq/Wk/Wv -> qh/kh/vhT^T);
//      3 = f32 store + bias (out-projection);
//      4 = QK^T fused bias+exp epilogue (no-max softmax; pre-scaled centers,
//          cq block rows cached in LDS)

template <int OUT>
__global__ __launch_bounds__(512, 2) void gemm256_kernel(
    const u16* __restrict__ A, const u16* __restrict__ Bt, void* __restrict__ C,
    const float* __restrict__ bias, const float2* __restrict__ cqp,
    const float2* __restrict__ crp, const float* __restrict__ bwp,
    float* __restrict__ psum, int NT, int nTn, int tmb,
    size_t ldaB, size_t ldbB, int ldc, size_t kspanB, size_t cstride, float alpha) {
  GEMM_SETUP;

  int band = 0;
  const u16* Bt2 = Bt;
  if (OUT == 2) { band = am0 >> 13; Bt2 = Bt + ((size_t)band << 20); }
  const char* Bgp2 = (const char*)Bt2 + kglob + scol;
  #define Bgp Bgp2

  short8 afP[4], afQ[4], bf[2][2][2];

  // prologue: tile0 -> buf0 (early-consumed units first)
  SGA(0, 0, 0); SGA(2, 0, 0); SGB(0, 0, 0); SGB(1, 0, 0);
  SGB(2, 0, 0); SGB(3, 0, 0); SGA(1, 0, 0); SGA(3, 0, 0);
  waitvm<0>();
  BARRIER;
  RDA4(afP, 0, 0, koff0);
  RDB2(0, 0, 0, koff0);

  for (int t = 0; t < NT; ++t) {
    const int bo = (t & 1) * 32768;
    const int nbo = bo ^ 32768;
    const int nb = (t & 1) ^ 1;
    const bool more = (t + 1 < NT);
    if (more) { SGA(0, t + 1, nb); SGA(2, t + 1, nb); }
    RDB2(1, 0, bo, koff0);
    MM8(afP, 0, 0, 0);
    if (more) { SGB(0, t + 1, nb); SGB(1, t + 1, nb); }
    RDA4(afQ, bo, 1, koff0);
    MM8(afP, 0, 1, 0);
    if (more) { SGB(2, t + 1, nb); SGB(3, t + 1, nb); }
    RDB2(0, 1, bo, koff1);
    MM8(afQ, 1, 1, 0);
    if (more) { SGA(1, t + 1, nb); SGA(3, t + 1, nb); }
    RDA4(afP, bo, 1, koff1);
    MM8(afQ, 1, 0, 0);
    RDB2(1, 1, bo, koff1);
    MM8(afP, 1, 0, 1);
    RDA4(afQ, bo, 0, koff1);
    MM8(afP, 1, 1, 1);
    MM8(afQ, 0, 1, 1);
    waitvm<4>();
    BARRIER;
    if (more) { RDA4(afP, nbo, 0, koff0); RDB2(0, 0, nbo, koff0); }
    MM8(afQ, 0, 0, 1);
    waitvm<0>();
    BARRIER;
  }
  #undef Bgp

  // ---------------- epilogue (16x16x32 C layout: col = lane&15, row = kq*4+j) ----
  if (OUT == 4) {
    const float sc = bwp[0] * 1.44269504f;
    const float eps2 = sc * sc * 1e-8f;
    float* psld = (float*)smem;                 // [0, 4KB): row partial sums
    float2* cqld = (float2*)(smemc + 4096);     // [4KB, 6KB): cached cq rows
    if (tid < 256) cqld[tid] = cqp[am0 + tid];
    __syncthreads();
    float2 crv[4];
#pragma unroll
    for (int fc2 = 0; fc2 < 4; ++fc2) crv[fc2] = crp[bn0 + wn * 64 + fc2 * 16 + lane_r];
#pragma unroll
    for (int fp = 0; fp < 8; ++fp) {
      float rs[4] = {0.f, 0.f, 0.f, 0.f};
      int rloc = wm * 128 + fp * 16 + kq * 4;
      int rbase = am0 + rloc;
#pragma unroll
      for (int j = 0; j < 4; ++j) {
        float2 cqv = cqld[rloc + j];
#pragma unroll
        for (int fc2 = 0; fc2 < 4; ++fc2) {
          float dx = cqv.x - crv[fc2].x, dy = cqv.y - crv[fc2].y;
          float d2v = fmaf(dx, dx, fmaf(dy, dy, eps2));
          float D;
          asm("v_sqrt_f32 %0, %1" : "=v"(D) : "v"(d2v));
          float l2 = fmaf(acc[fp][fc2][j], 1.44269504f, -D);
          float pv;
          asm("v_exp_f32 %0, %1" : "=v"(pv) : "v"(l2));
          rs[j] += pv;
          int col = bn0 + wn * 64 + fc2 * 16 + lane_r;
          ((u16*)C)[(size_t)(rbase + j) * ldc + col] = f2bf(pv);
        }
      }
#pragma unroll
      for (int j = 0; j < 4; ++j) {
        float s = rs[j];
        s += __shfl_xor(s, 1); s += __shfl_xor(s, 2);
        s += __shfl_xor(s, 4); s += __shfl_xor(s, 8);
        if (lane_r == 0)
          psld[(rloc + j) * 4 + wn] = s;
      }
    }
    __syncthreads();
    if (tid < 256) {
      float s = psld[tid * 4] + psld[tid * 4 + 1] + psld[tid * 4 + 2] + psld[tid * 4 + 3];
      psum[(size_t)tn * NQ + am0 + tid] = s;
    }
    return;
  }
#pragma unroll
  for (int fp = 0; fp < 8; ++fp) {
#pragma unroll
    for (int fc2 = 0; fc2 < 4; ++fc2) {
      int row = am0 + wm * 128 + fp * 16 + kq * 4;
      int col = bn0 + wn * 64 + fc2 * 16 + lane_r;
      if (OUT == 0) {
#pragma unroll
        for (int j = 0; j < 4; ++j)
          ((u16*)C)[(size_t)(row + j) * ldc + col] = f2bf(acc[fp][fc2][j] * alpha);
      } else if (OUT == 1) {
        u16* Cp = (u16*)C + cstride * blockIdx.y;
#pragma unroll
        for (int j = 0; j < 4; ++j)
          Cp[(size_t)(row + j) * ldc + col] = f2bf(acc[fp][fc2][j]);
      } else if (OUT == 3) {
        float* Cf = (float*)C;
        float bv = bias[col];
#pragma unroll
        for (int j = 0; j < 4; ++j)
          Cf[(size_t)(row + j) * ldc + col] = acc[fp][fc2][j] * alpha + bv;
      } else {
        int arow = row & 8191;
        if (band < 2) {
          u16* D = (u16*)C + ((size_t)band << 23);  // qh / kh
          float a2 = (band == 0) ? 0.03125f : 1.f;
#pragma unroll
          for (int j = 0; j < 4; ++j)
            D[(size_t)(arow + j) * DIM + col] = f2bf(acc[fp][fc2][j] * a2);
        } else {
          u16* D = (u16*)C + ((size_t)2 << 23);     // vhT (transposed)
          u16x4 pk;
#pragma unroll
          for (int j = 0; j < 4; ++j) pk[j] = f2bf(acc[fp][fc2][j]);
          *(u16x4*)&D[(size_t)col * NK + arow] = pk;
        }
      }
    }
  }
}

// ---------------- split-K=2 combine + inline rowsum-inverse + normalize ----------
// block b covers rows {2b, 2b+1}; threads 0-63 reduce the 32 psum partials per
// row (shfl within 32-lane groups), then all threads normalize + pack bf16.

__global__ __launch_bounds__(256) void combine2_kernel(
    const u16x8* __restrict__ p, const float* __restrict__ psum,
    u16x8* __restrict__ out) {
  __shared__ float sinv[2];
  const size_t st = (size_t)NQ * DIM / 8;
  const int t = threadIdx.x;
  const int r0 = blockIdx.x * 2;
  if (t < 64) {
    int rr = r0 + (t >> 5);
    float s = psum[(size_t)(t & 31) * NQ + rr];
    s += __shfl_xor(s, 1); s += __shfl_xor(s, 2); s += __shfl_xor(s, 4);
    s += __shfl_xor(s, 8); s += __shfl_xor(s, 16);
    if ((t & 31) == 0) sinv[t >> 5] = 1.f / s;
  }
  __syncthreads();
  size_t i = (size_t)blockIdx.x * 256 + t;
  u16x8 a = p[i], b = p[i + st];
  float iv = sinv[t >> 7];
  u16x8 o;
#pragma unroll
  for (int j = 0; j < 8; ++j)
    o[j] = f2bf((bf2f(a[j]) + bf2f(b[j])) * iv);
  out[i] = o;
}

// ---------------- fused bias + row softmax, bf16 in place (fallback path) --------

__global__ __launch_bounds__(256) void softmax_bias_bf16_kernel(
    u16* __restrict__ S, const float2* __restrict__ cq, const float2* __restrict__ cr,
    const float* __restrict__ bwp, int qr0) {
  __shared__ float red[256];
  const int t = threadIdx.x;
  u16* row = S + (size_t)blockIdx.x * NK;
  const float2 cqv = cq[qr0 + blockIdx.x];
  const float bw = bwp[0];

  float l[32];
  float mx = -1e30f;
#pragma unroll
  for (int i = 0; i < 4; ++i) {
    int base = (i * 256 + t) * 8;
    u16x8 u = *(const u16x8*)&row[base];
#pragma unroll
    for (int j = 0; j < 8; ++j) {
      float x = bf2f(u[j]);
      float2 c = cr[base + j];
      float dx = cqv.x - c.x, dy = cqv.y - c.y;
      float lv = x - bw * sqrtf(dx * dx + dy * dy + 1e-8f);
      l[i * 8 + j] = lv;
      mx = fmaxf(mx, lv);
    }
  }
  red[t] = mx; __syncthreads();
  for (int s = 128; s > 0; s >>= 1) { if (t < s) red[t] = fmaxf(red[t], red[t + s]); __syncthreads(); }
  mx = red[0]; __syncthreads();

  float sum = 0.f;
#pragma unroll
  for (int i = 0; i < 32; ++i) { float e = __expf(l[i] - mx); l[i] = e; sum += e; }
  red[t] = sum; __syncthreads();
  for (int s = 128; s > 0; s >>= 1) { if (t < s) red[t] += red[t + s]; __syncthreads(); }
  float inv = 1.f / red[0];

#pragma unroll
  for (int i = 0; i < 4; ++i) {
    int base = (i * 256 + t) * 8;
    u16x8 o;
#pragma unroll
    for (int j = 0; j < 8; ++j) o[j] = f2bf(l[i * 8 + j] * inv);
    *(u16x8*)&row[base] = o;
  }
}

// ---------------- host ----------------

extern "C" void kernel_launch(void* const* d_in, const int* in_sizes, int n_in,
                              void* d_out, int out_size, void* d_ws, size_t ws_size,
                              hipStream_t stream) {
  const float* q  = (const float*)d_in[0];
  const float* k  = (const float*)d_in[1];
  const float* v  = (const float*)d_in[2];
  const float* rb = (const float*)d_in[3];
  const float* qb = (const float*)d_in[4];
  const float* Wq = (const float*)d_in[5];
  const float* Wk = (const float*)d_in[6];
  const float* Wv = (const float*)d_in[7];
  const float* Wp = (const float*)d_in[8];
  const float* bp = (const float*)d_in[9];
  const float* W1 = (const float*)d_in[10];
  const float* b1 = (const float*)d_in[11];
  const float* W2 = (const float*)d_in[12];
  const float* b2 = (const float*)d_in[13];
  float* out = (float*)d_out;

  // qbf|kbf dead after proj -> hold the two 16 MB bf16 split-K partials of PV.
  char* p = (char*)d_ws;
  const size_t PROJB = (size_t)NQ * DIM * sizeof(u16);  // 16 MB
  u16* qbf = (u16*)p;            p += PROJB;
  u16* kbf = (u16*)p;            p += PROJB;
  u16* vbf = (u16*)p;            p += PROJB;
  u16* qh  = (u16*)p;            p += PROJB;
  u16* kh  = (u16*)p;            p += PROJB;
  u16* vhT = (u16*)p;            p += PROJB;
  u16* WqT = (u16*)p;            p += (size_t)DIM * DIM * 2;
  u16* WkT = (u16*)p;            p += (size_t)DIM * DIM * 2;
  u16* WvT = (u16*)p;            p += (size_t)DIM * DIM * 2;
  u16* WpT = (u16*)p;            p += (size_t)DIM * DIM * 2;
  float* cq  = (float*)p;        p += 2 * NQ * 4;
  float* cr  = (float*)p;        p += 2 * NK * 4;
  float* cqs = (float*)p;        p += 2 * NQ * 4;
  float* crs = (float*)p;        p += 2 * NK * 4;
  float* ps  = (float*)p;        p += 32 * DIM * 4;   // fallback var partials
  float* pq  = (float*)p;        p += 32 * DIM * 4;
  float* gfv = (float*)p;        p += DIM * 4;
  float* h1p = (float*)p;        p += 8 * 2048 * 4;
  float* bw  = (float*)p;        p += 64;
  float* psum = (float*)p;       p += (size_t)32 * NQ * 4;
  size_t fixed_b = (size_t)(p - (char*)d_ws);

  int SR = 256;
  for (int cand = 8192; cand >= 256; cand >>= 1) {
    if (fixed_b + (size_t)cand * (NK + DIM) * 2 <= ws_size) { SR = cand; break; }
  }
  u16* Sbuf = (u16*)p;
  u16* Obuf = Sbuf + (size_t)SR * NK;

  const int N4 = NQ * DIM / 4;

  if (SR == 8192) {
    // var partials fused into f2bf3's k-branch; partials in not-yet-written Sbuf
    float* psB = (float*)Sbuf;
    float* pqB = psB + (size_t)1024 * DIM;
    f2bf3_kernel<<<dim3(1024, 3), 256, 0, stream>>>(
        (const float4*)q, (const float4*)k, (const float4*)v,
        (u16x4*)qbf, (u16x4*)kbf, (u16x4*)vbf, N4, psB, pqB);
    var_reduce_kernel<<<32, 256, 0, stream>>>(psB, pqB, gfv);
  } else {
    f2bf3_kernel<<<dim3(1024, 3), 256, 0, stream>>>(
        (const float4*)q, (const float4*)k, (const float4*)v,
        (u16x4*)qbf, (u16x4*)kbf, (u16x4*)vbf, N4, nullptr, nullptr);
    var_partial_kernel<<<dim3(4, 32), 256, 0, stream>>>(k, ps, pq);
    gfv_kernel<<<4, 256, 0, stream>>>(ps, pq, gfv, 32);
  }
  h1_partial_kernel<<<dim3(8, 8), 256, 0, stream>>>(gfv, W1, h1p);
  bw_kernel<<<1, 256, 0, stream>>>(h1p, b1, W2, b2, bw);
  centers_kernel<<<32, 256, 0, stream>>>((const float4*)qb, (const float4*)rb, bw,
                                         (float2*)cq, (float2*)cr,
                                         (float2*)cqs, (float2*)crs);
  wtrans4_kernel<<<dim3(16, 16, 4), 256, 0, stream>>>(Wq, Wk, Wv, Wp, WqT, WkT, WvT, WpT);

  // fused q/k/v projections (R5 schedule)
  gemm256_kernel<2><<<dim3(384, 1), 512, 0, stream>>>(
      qbf, WqT, qh, nullptr, nullptr, nullptr, nullptr, nullptr,
      16, 4, 12, 2048, 2048, DIM, 0, 0, 1.f);

  if (SR == 8192) {
    // S = exp(qh @ kh^T - bw*dist) fused (scaled centers); row sums -> psum
    gemm256_kernel<4><<<dim3(1024, 1), 512, 0, stream>>>(
        qh, kh, Sbuf, nullptr, (const float2*)cqs, (const float2*)crs, bw, psum,
        16, 32, 4, 2048, 2048, NK, 0, 0, 1.f);
    // O' = P' @ vh, split-K=2 (256 blocks = 1/CU, NT=64), bf16 partials in qbf|kbf
    gemm256_kernel<1><<<dim3(128, 2), 512, 0, stream>>>(
        Sbuf, vhT, qbf, nullptr, nullptr, nullptr, nullptr, nullptr,
        64, 4, 4, 16384, 16384, DIM, 8192, (size_t)NQ * DIM, 1.f);
    // combine partials + inline rowsum-inverse + normalize
    combine2_kernel<<<4096, 256, 0, stream>>>((const u16x8*)qbf, psum, (u16x8*)Obuf);
    // out = O @ Wp + bp
    gemm256_kernel<3><<<dim3(128, 1), 512, 0, stream>>>(
        Obuf, WpT, out, bp, nullptr, nullptr, nullptr, nullptr,
        16, 4, 4, 2048, 2048, DIM, 0, 0, 1.f);
  } else {
    for (int s0 = 0; s0 < NQ; s0 += SR) {
      bgemm_kernel<1><<<dim3(NK / TN, SR / TM), 256, 0, stream>>>(
          qh + (size_t)s0 * DIM, kh, Sbuf, nullptr, SR, NK, DIM, NK, 1.f);
      softmax_bias_bf16_kernel<<<SR, 256, 0, stream>>>(
          Sbuf, (const float2*)cq, (const float2*)cr, bw, s0);
      bgemm_kernel<1><<<dim3(DIM / TN, SR / TM), 256, 0, stream>>>(
          Sbuf, vhT, Obuf, nullptr, SR, DIM, NK, DIM, 1.f);
      bgemm_kernel<0><<<dim3(DIM / TN, SR / TM), 256, 0, stream>>>(
          Obuf, WpT, out + (size_t)s0 * DIM, bp, SR, DIM, DIM, DIM, 1.f);
    }
  }
}